// Round 1
// baseline (1197.342 us; speedup 1.0000x reference)
//
#include <hip/hip_runtime.h>

// MultiHeadSelfAttention: B=4, S=1024, D=512(d_model, also per-head dim), H=8
// out  = [B*S, D]   fp32  at d_out
// attn = [H*B, S, S] fp32 at d_out + B*S*D
// d_ws layout: q bf16 [4096,4096], k bf16, v bf16  (ctx reuses q buffer)
// ws needed: 3 * 4096*4096*2 = 100,663,296 bytes

typedef unsigned short u16;
typedef __attribute__((ext_vector_type(8))) short short8;
typedef __attribute__((ext_vector_type(4))) float f32x4;
typedef __attribute__((ext_vector_type(2))) unsigned int u32x2;

#define BM 128
#define BN 128
#define BK 32

__device__ __forceinline__ u16 f2bf(float f) {
    union { float f; unsigned u; } v; v.f = f;
    unsigned u = v.u;
    u += 0x7fffu + ((u >> 16) & 1u);   // round-to-nearest-even
    return (u16)(u >> 16);
}

// C = scale * (A @ B) + bias.  A:[M,K], B: NN=[K,N] / BT=[N,K], row-major.
// Batch via blockIdx.z: zh = z/nb, zb = z%nb; per-operand (h,b) element strides.
template<bool AF32, bool BF32, bool BT, bool OUTF32>
__global__ __launch_bounds__(256)
void gemm_kernel(const void* __restrict__ Ap, int lda, long long sAh, long long sAb,
                 const void* __restrict__ Bp, int ldb, long long sBh, long long sBb,
                 void* __restrict__ Cp, int ldc, long long sCh, long long sCb,
                 int K, const float* __restrict__ bias, float scale, int nb)
{
    __shared__ __attribute__((aligned(16))) u16 Alds[BM][BK];   // [m][k]
    __shared__ __attribute__((aligned(16))) u16 Blds[BN][BK];   // [n][k]

    const int z  = blockIdx.z;
    const int zh = z / nb, zb = z % nb;
    const long long aoff = (long long)zh * sAh + (long long)zb * sAb;
    const long long boff = (long long)zh * sBh + (long long)zb * sBb;
    const long long coff = (long long)zh * sCh + (long long)zb * sCb;

    const int m0 = blockIdx.y * BM;
    const int n0 = blockIdx.x * BN;

    const int tid  = threadIdx.x;
    const int lane = tid & 63;
    const int wave = tid >> 6;
    const int wm = (wave >> 1) * 64;   // wave's 64x64 quadrant
    const int wn = (wave & 1) * 64;

    const float* Afp = (const float*)Ap + aoff;
    const u16*   Abf = (const u16*)Ap + aoff;
    const float* Bfp = (const float*)Bp + boff;
    const u16*   Bbf = (const u16*)Bp + boff;

    f32x4 acc[4][4] = {};

    for (int kt = 0; kt < K; kt += BK) {
        __syncthreads();
        // ---- stage A tile -> Alds[m][k] (k-contiguous) ----
        if (AF32) {
            #pragma unroll
            for (int i = 0; i < 4; ++i) {
                int idx = i * 256 + tid;
                int row = idx >> 3;
                int kq  = (idx & 7) << 2;
                f32x4 v = *(const f32x4*)(Afp + (long long)(m0 + row) * lda + (kt + kq));
                u32x2 p;
                p.x = (unsigned)f2bf(v.x) | ((unsigned)f2bf(v.y) << 16);
                p.y = (unsigned)f2bf(v.z) | ((unsigned)f2bf(v.w) << 16);
                *(u32x2*)(&Alds[row][kq]) = p;
            }
        } else {
            #pragma unroll
            for (int i = 0; i < 2; ++i) {
                int idx = i * 256 + tid;
                int row = idx >> 2;
                int kq  = (idx & 3) << 3;
                *(short8*)(&Alds[row][kq]) =
                    *(const short8*)(Abf + (long long)(m0 + row) * lda + (kt + kq));
            }
        }
        // ---- stage B tile -> Blds[n][k] ----
        if (BT) {
            if (BF32) {
                #pragma unroll
                for (int i = 0; i < 4; ++i) {
                    int idx = i * 256 + tid;
                    int row = idx >> 3;
                    int kq  = (idx & 7) << 2;
                    f32x4 v = *(const f32x4*)(Bfp + (long long)(n0 + row) * ldb + (kt + kq));
                    u32x2 p;
                    p.x = (unsigned)f2bf(v.x) | ((unsigned)f2bf(v.y) << 16);
                    p.y = (unsigned)f2bf(v.z) | ((unsigned)f2bf(v.w) << 16);
                    *(u32x2*)(&Blds[row][kq]) = p;
                }
            } else {
                #pragma unroll
                for (int i = 0; i < 2; ++i) {
                    int idx = i * 256 + tid;
                    int row = idx >> 2;
                    int kq  = (idx & 3) << 3;
                    *(short8*)(&Blds[row][kq]) =
                        *(const short8*)(Bbf + (long long)(n0 + row) * ldb + (kt + kq));
                }
            }
        } else {
            if (BF32) {
                #pragma unroll
                for (int i = 0; i < 4; ++i) {
                    int idx = i * 256 + tid;
                    int krow = idx >> 5;
                    int nq   = (idx & 31) << 2;
                    f32x4 v = *(const f32x4*)(Bfp + (long long)(kt + krow) * ldb + (n0 + nq));
                    Blds[nq + 0][krow] = f2bf(v.x);
                    Blds[nq + 1][krow] = f2bf(v.y);
                    Blds[nq + 2][krow] = f2bf(v.z);
                    Blds[nq + 3][krow] = f2bf(v.w);
                }
            } else {
                #pragma unroll
                for (int i = 0; i < 2; ++i) {
                    int idx = i * 256 + tid;
                    int krow = idx >> 4;
                    int nq   = (idx & 15) << 3;
                    union { short8 v; u16 e[8]; } uv;
                    uv.v = *(const short8*)(Bbf + (long long)(kt + krow) * ldb + (n0 + nq));
                    #pragma unroll
                    for (int j = 0; j < 8; ++j) Blds[nq + j][krow] = uv.e[j];
                }
            }
        }
        __syncthreads();

        // ---- compute: 4x4 tiles of 16x16x32 MFMA ----
        const int kq = (lane >> 4) << 3;   // quad*8
        const int fr = lane & 15;
        short8 af[4], bfr[4];
        #pragma unroll
        for (int im = 0; im < 4; ++im)
            af[im] = *(const short8*)(&Alds[wm + im * 16 + fr][kq]);
        #pragma unroll
        for (int in = 0; in < 4; ++in)
            bfr[in] = *(const short8*)(&Blds[wn + in * 16 + fr][kq]);
        #pragma unroll
        for (int im = 0; im < 4; ++im)
            #pragma unroll
            for (int in = 0; in < 4; ++in)
                acc[im][in] = __builtin_amdgcn_mfma_f32_16x16x32_bf16(
                    af[im], bfr[in], acc[im][in], 0, 0, 0);
    }

    // ---- epilogue: C[row=(lane>>4)*4+r][col=lane&15] ----
    float* Cfp = (float*)Cp + coff;
    u16*   Cbf = (u16*)Cp + coff;
    const int rb  = (lane >> 4) << 2;
    const int col = lane & 15;
    #pragma unroll
    for (int im = 0; im < 4; ++im) {
        #pragma unroll
        for (int r = 0; r < 4; ++r) {
            int row = m0 + wm + im * 16 + rb + r;
            #pragma unroll
            for (int in = 0; in < 4; ++in) {
                int cc = n0 + wn + in * 16 + col;
                float v = acc[im][in][r] * scale;
                if (bias) v += bias[cc];
                if (OUTF32) Cfp[(long long)row * ldc + cc] = v;
                else        Cbf[(long long)row * ldc + cc] = f2bf(v);
            }
        }
    }
}

// In-place softmax over rows of 1024 fp32. One 256-thread block per row.
__global__ __launch_bounds__(256)
void softmax_kernel(float* __restrict__ attn)
{
    const long long row = blockIdx.x;
    float* p = attn + row * 1024;
    const int tid  = threadIdx.x;
    const int lane = tid & 63;
    const int wave = tid >> 6;
    __shared__ float red[8];

    f32x4 v = *(f32x4*)(p + tid * 4);
    float mx = fmaxf(fmaxf(v.x, v.y), fmaxf(v.z, v.w));
    #pragma unroll
    for (int off = 1; off < 64; off <<= 1)
        mx = fmaxf(mx, __shfl_xor(mx, off, 64));
    if (lane == 0) red[wave] = mx;
    __syncthreads();
    mx = fmaxf(fmaxf(red[0], red[1]), fmaxf(red[2], red[3]));

    v.x = __expf(v.x - mx);
    v.y = __expf(v.y - mx);
    v.z = __expf(v.z - mx);
    v.w = __expf(v.w - mx);
    float s = v.x + v.y + v.z + v.w;
    #pragma unroll
    for (int off = 1; off < 64; off <<= 1)
        s += __shfl_xor(s, off, 64);
    if (lane == 0) red[4 + wave] = s;
    __syncthreads();
    s = red[4] + red[5] + red[6] + red[7];
    float inv = 1.0f / s;
    v.x *= inv; v.y *= inv; v.z *= inv; v.w *= inv;
    *(f32x4*)(p + tid * 4) = v;
}

extern "C" void kernel_launch(void* const* d_in, const int* in_sizes, int n_in,
                              void* d_out, int out_size, void* d_ws, size_t ws_size,
                              hipStream_t stream)
{
    const float* x  = (const float*)d_in[0];
    const float* Wq = (const float*)d_in[1];
    const float* bq = (const float*)d_in[2];
    const float* Wk = (const float*)d_in[3];
    const float* bk = (const float*)d_in[4];
    const float* Wv = (const float*)d_in[5];
    const float* bv = (const float*)d_in[6];
    const float* Wo = (const float*)d_in[7];
    const float* bo = (const float*)d_in[8];

    const int B = 4, S = 1024, D = 512, H = 8;
    const int HD = H * D;   // 4096
    const int BS = B * S;   // 4096

    float* out  = (float*)d_out;                     // [4096, 512]
    float* attn = out + (long long)BS * D;           // [32, 1024, 1024]

    u16* qb   = (u16*)d_ws;                          // [4096,4096] bf16
    u16* kb   = qb + (long long)BS * HD;
    u16* vb   = kb + (long long)BS * HD;
    u16* ctxb = qb;                                  // q dead after scores

    dim3 blk(256);

    // 1) QKV projections: [4096,512] @ [512,4096] -> bf16
    {
        dim3 g(HD / BN, BS / BM, 1);
        gemm_kernel<true,true,false,false><<<g, blk, 0, stream>>>(
            x, D, 0, 0, Wq, HD, 0, 0, qb, HD, 0, 0, D, bq, 1.0f, 1);
        gemm_kernel<true,true,false,false><<<g, blk, 0, stream>>>(
            x, D, 0, 0, Wk, HD, 0, 0, kb, HD, 0, 0, D, bk, 1.0f, 1);
        gemm_kernel<true,true,false,false><<<g, blk, 0, stream>>>(
            x, D, 0, 0, Wv, HD, 0, 0, vb, HD, 0, 0, D, bv, 1.0f, 1);
    }
    // 2) scores = q @ k^T / 512 per (h,b) -> fp32 attn region
    {
        dim3 g(S / BN, S / BM, H * B);
        gemm_kernel<false,false,true,true><<<g, blk, 0, stream>>>(
            qb, HD, D, (long long)S * HD,
            kb, HD, D, (long long)S * HD,
            attn, S, (long long)B * S * S, (long long)S * S,
            D, nullptr, 1.0f / (float)D, B);
    }
    // 3) row softmax in place
    softmax_kernel<<<dim3(H * B * S), blk, 0, stream>>>(attn);
    // 4) ctx = attn @ v per (h,b) -> bf16 (reuses q buffer)
    {
        dim3 g(D / BN, S / BM, H * B);
        gemm_kernel<true,false,false,false><<<g, blk, 0, stream>>>(
            attn, S, (long long)B * S * S, (long long)S * S,
            vb, HD, D, (long long)S * HD,
            ctxb, HD, D, (long long)S * HD,
            S, nullptr, 1.0f, B);
    }
    // 5) out = ctx @ Wo + bo -> fp32
    {
        dim3 g(D / BN, BS / BM, 1);
        gemm_kernel<false,true,false,true><<<g, blk, 0, stream>>>(
            ctxb, HD, 0, 0, Wo, D, 0, 0, out, D, 0, 0, HD, bo, 1.0f, 1);
    }
}

// Round 2
// 629.144 us; speedup vs baseline: 1.9031x; 1.9031x over previous
//
#include <hip/hip_runtime.h>

// MultiHeadSelfAttention: B=4, S=1024, D=512(d_model = per-head dim), H=8
// out  = [B*S, D]    fp32 at d_out
// attn = [H*B, S, S] fp32 at d_out + B*S*D
//
// All GEMMs are BT (B given as [N][K] bf16, k-contiguous) -> conflict-free
// short8/global_load_lds staging. Weights pre-transposed+converted once.
//
// d_ws layout (88.1 MB):
//   xb   bf16 [4096,512]    4 MB
//   WqT  bf16 [4096,512]    4 MB
//   WkT  bf16 [4096,512]    4 MB
//   WvT  bf16 [4096,512]    4 MB
//   WoT  bf16 [512,4096]    4 MB
//   buf1 bf16 [4096,4096]  33.5 MB   (q -> vb -> ctx)
//   buf2 bf16 [4096,4096]  33.5 MB   (k -> vT)

typedef unsigned short u16;
typedef __attribute__((ext_vector_type(8))) short short8;
typedef __attribute__((ext_vector_type(4))) float f32x4;
typedef __attribute__((ext_vector_type(2))) unsigned int u32x2;

#define BM 128
#define BN 128
#define BK 32

__device__ __forceinline__ u16 f2bf(float f) {
    union { float f; unsigned u; } v; v.f = f;
    unsigned u = v.u;
    u += 0x7fffu + ((u >> 16) & 1u);   // round-to-nearest-even
    return (u16)(u >> 16);
}

__device__ __forceinline__ void gl2lds16(const void* g, void* l) {
    __builtin_amdgcn_global_load_lds(
        (const __attribute__((address_space(1))) void*)g,
        (__attribute__((address_space(3))) void*)l, 16, 0, 0);
}

// C = scale * (A @ B^T) + bias.  A:[M,K] (fp32 or bf16), B:[N,K] bf16, row-major.
// Batch via blockIdx.z: zh = z/nb, zb = z%nb.
template<bool AF32, bool OUTF32>
__global__ __launch_bounds__(256)
void gemm_bt(const void* __restrict__ Ap, int lda, long long sAh, long long sAb,
             const u16* __restrict__ Bp, int ldb, long long sBh, long long sBb,
             void* __restrict__ Cp, int ldc, long long sCh, long long sCb,
             int K, const float* __restrict__ bias, float scale, int nb)
{
    __shared__ __attribute__((aligned(16))) u16 Alds[BM][BK];   // [m][k]
    __shared__ __attribute__((aligned(16))) u16 Blds[BN][BK];   // [n][k]

    const int z  = blockIdx.z;
    const int zh = z / nb, zb = z % nb;

    const int m0 = blockIdx.y * BM;
    const int n0 = blockIdx.x * BN;

    const int tid  = threadIdx.x;
    const int lane = tid & 63;
    const int wave = tid >> 6;
    const int wm = (wave >> 1) * 64;
    const int wn = (wave & 1) * 64;

    const float* Afp = (const float*)Ap + (long long)zh * sAh + (long long)zb * sAb;
    const u16*   Abf = (const u16*)Ap + (long long)zh * sAh + (long long)zb * sAb;
    const u16*   Bbf = Bp + (long long)zh * sBh + (long long)zb * sBb;

    f32x4 acc[4][4] = {};

    for (int kt = 0; kt < K; kt += BK) {
        __syncthreads();
        // ---- stage A tile -> Alds[m][k] ----
        if (AF32) {
            #pragma unroll
            for (int i = 0; i < 4; ++i) {
                int idx = i * 256 + tid;
                int row = idx >> 3;
                int kq  = (idx & 7) << 2;
                f32x4 v = *(const f32x4*)(Afp + (long long)(m0 + row) * lda + (kt + kq));
                u32x2 p;
                p.x = (unsigned)f2bf(v.x) | ((unsigned)f2bf(v.y) << 16);
                p.y = (unsigned)f2bf(v.z) | ((unsigned)f2bf(v.w) << 16);
                *(u32x2*)(&Alds[row][kq]) = p;
            }
        } else {
            #pragma unroll
            for (int i = 0; i < 2; ++i) {
                int idx = i * 256 + tid;
                int row = idx >> 2;
                int kq  = (idx & 3) << 3;
                gl2lds16(Abf + (long long)(m0 + row) * lda + (kt + kq), &Alds[row][kq]);
            }
        }
        // ---- stage B tile -> Blds[n][k] ----
        #pragma unroll
        for (int i = 0; i < 2; ++i) {
            int idx = i * 256 + tid;
            int row = idx >> 2;
            int kq  = (idx & 3) << 3;
            gl2lds16(Bbf + (long long)(n0 + row) * ldb + (kt + kq), &Blds[row][kq]);
        }
        __syncthreads();

        // ---- compute: 4x4 tiles of 16x16x32 MFMA ----
        const int kq = (lane >> 4) << 3;
        const int fr = lane & 15;
        short8 af[4], bfr[4];
        #pragma unroll
        for (int im = 0; im < 4; ++im)
            af[im] = *(const short8*)(&Alds[wm + im * 16 + fr][kq]);
        #pragma unroll
        for (int in = 0; in < 4; ++in)
            bfr[in] = *(const short8*)(&Blds[wn + in * 16 + fr][kq]);
        #pragma unroll
        for (int im = 0; im < 4; ++im)
            #pragma unroll
            for (int in = 0; in < 4; ++in)
                acc[im][in] = __builtin_amdgcn_mfma_f32_16x16x32_bf16(
                    af[im], bfr[in], acc[im][in], 0, 0, 0);
    }

    // ---- epilogue: C[row=(lane>>4)*4+r][col=lane&15] ----
    float* Cfp = (float*)Cp + (long long)zh * sCh + (long long)zb * sCb;
    u16*   Cbf = (u16*)Cp + (long long)zh * sCh + (long long)zb * sCb;
    const int rb  = (lane >> 4) << 2;
    const int col = lane & 15;
    #pragma unroll
    for (int im = 0; im < 4; ++im) {
        #pragma unroll
        for (int r = 0; r < 4; ++r) {
            int row = m0 + wm + im * 16 + rb + r;
            #pragma unroll
            for (int in = 0; in < 4; ++in) {
                int cc = n0 + wn + in * 16 + col;
                float v = acc[im][in][r] * scale;
                if (bias) v += bias[cc];
                if (OUTF32) Cfp[(long long)row * ldc + cc] = v;
                else        Cbf[(long long)row * ldc + cc] = f2bf(v);
            }
        }
    }
}

// In-place softmax over rows of 1024 fp32. One 256-thread block per row.
__global__ __launch_bounds__(256)
void softmax_kernel(float* __restrict__ attn)
{
    const long long row = blockIdx.x;
    float* p = attn + row * 1024;
    const int tid  = threadIdx.x;
    const int lane = tid & 63;
    const int wave = tid >> 6;
    __shared__ float red[8];

    f32x4 v = *(f32x4*)(p + tid * 4);
    float mx = fmaxf(fmaxf(v.x, v.y), fmaxf(v.z, v.w));
    #pragma unroll
    for (int off = 1; off < 64; off <<= 1)
        mx = fmaxf(mx, __shfl_xor(mx, off, 64));
    if (lane == 0) red[wave] = mx;
    __syncthreads();
    mx = fmaxf(fmaxf(red[0], red[1]), fmaxf(red[2], red[3]));

    v.x = __expf(v.x - mx);
    v.y = __expf(v.y - mx);
    v.z = __expf(v.z - mx);
    v.w = __expf(v.w - mx);
    float s = v.x + v.y + v.z + v.w;
    #pragma unroll
    for (int off = 1; off < 64; off <<= 1)
        s += __shfl_xor(s, off, 64);
    if (lane == 0) red[4 + wave] = s;
    __syncthreads();
    s = red[4] + red[5] + red[6] + red[7];
    float inv = 1.0f / s;
    v.x *= inv; v.y *= inv; v.z *= inv; v.w *= inv;
    *(f32x4*)(p + tid * 4) = v;
}

// x fp32 -> bf16 elementwise (n4 = quads)
__global__ __launch_bounds__(256)
void cvt_kernel(const float* __restrict__ in, u16* __restrict__ out)
{
    long long i = (long long)blockIdx.x * 256 + threadIdx.x;
    f32x4 v = *(const f32x4*)(in + i * 4);
    u32x2 p;
    p.x = (unsigned)f2bf(v.x) | ((unsigned)f2bf(v.y) << 16);
    p.y = (unsigned)f2bf(v.z) | ((unsigned)f2bf(v.w) << 16);
    *(u32x2*)(out + i * 4) = p;
}

// transpose fp32 [R][C] -> bf16 [C][R]; 64x64 tiles, grid (C/64, R/64)
__global__ __launch_bounds__(256)
void wtrans_kernel(const float* __restrict__ in, u16* __restrict__ out, int R, int C)
{
    __shared__ __attribute__((aligned(16))) u16 t[64][72];
    const int r0 = blockIdx.y * 64, c0 = blockIdx.x * 64;
    const int tid = threadIdx.x;
    const int lr = tid >> 4;
    const int lc = (tid & 15) << 2;
    #pragma unroll
    for (int j = 0; j < 4; ++j) {
        int rr = lr + j * 16;
        f32x4 v = *(const f32x4*)(in + (long long)(r0 + rr) * C + c0 + lc);
        u32x2 p;
        p.x = (unsigned)f2bf(v.x) | ((unsigned)f2bf(v.y) << 16);
        p.y = (unsigned)f2bf(v.z) | ((unsigned)f2bf(v.w) << 16);
        *(u32x2*)(&t[rr][lc]) = p;
    }
    __syncthreads();
    const int oc = tid >> 2;
    const int rs = (tid & 3) << 4;
    union { short8 v; u16 e[8]; } a, b;
    #pragma unroll
    for (int j = 0; j < 8; ++j) a.e[j] = t[rs + j][oc];
    #pragma unroll
    for (int j = 0; j < 8; ++j) b.e[j] = t[rs + 8 + j][oc];
    u16* o = out + (long long)(c0 + oc) * R + r0 + rs;
    *(short8*)o = a.v;
    *(short8*)(o + 8) = b.v;
}

// per (h,b): vb[S][HD] slice cols [h*D, h*D+512) -> vT[(h*B+b)][D][S]
// grid (S/64, D/64, H*B)
__global__ __launch_bounds__(256)
void vtrans_kernel(const u16* __restrict__ vb, u16* __restrict__ vT)
{
    __shared__ __attribute__((aligned(16))) u16 t[64][72];
    const int S = 1024, D = 512, HD = 4096;
    const int hb = blockIdx.z, h = hb >> 2, b = hb & 3;
    const int s0 = blockIdx.x * 64, d0 = blockIdx.y * 64;
    const int tid = threadIdx.x;
    const int lr = tid >> 3;
    const int lc = (tid & 7) << 3;
    #pragma unroll
    for (int j = 0; j < 2; ++j) {
        int rr = lr + j * 32;
        *(short8*)(&t[rr][lc]) =
            *(const short8*)(vb + (long long)(b * S + s0 + rr) * HD + h * D + d0 + lc);
    }
    __syncthreads();
    const int od = tid >> 2;
    const int ss = (tid & 3) << 4;
    union { short8 v; u16 e[8]; } a, c;
    #pragma unroll
    for (int j = 0; j < 8; ++j) a.e[j] = t[ss + j][od];
    #pragma unroll
    for (int j = 0; j < 8; ++j) c.e[j] = t[ss + 8 + j][od];
    u16* o = vT + ((long long)hb * D + d0 + od) * S + s0 + ss;
    *(short8*)o = a.v;
    *(short8*)(o + 8) = c.v;
}

extern "C" void kernel_launch(void* const* d_in, const int* in_sizes, int n_in,
                              void* d_out, int out_size, void* d_ws, size_t ws_size,
                              hipStream_t stream)
{
    const float* x  = (const float*)d_in[0];
    const float* Wq = (const float*)d_in[1];
    const float* bq = (const float*)d_in[2];
    const float* Wk = (const float*)d_in[3];
    const float* bk = (const float*)d_in[4];
    const float* Wv = (const float*)d_in[5];
    const float* bv = (const float*)d_in[6];
    const float* Wo = (const float*)d_in[7];
    const float* bo = (const float*)d_in[8];

    const int B = 4, S = 1024, D = 512, H = 8;
    const int HD = H * D;   // 4096
    const int BS = B * S;   // 4096

    float* out  = (float*)d_out;                     // [4096, 512]
    float* attn = out + (long long)BS * D;           // [32, 1024, 1024]

    u16* xb   = (u16*)d_ws;                          // [4096,512]
    u16* WqT  = xb  + (long long)BS * D;             // [4096,512]
    u16* WkT  = WqT + (long long)HD * D;
    u16* WvT  = WkT + (long long)HD * D;
    u16* WoT  = WvT + (long long)HD * D;             // [512,4096]
    u16* buf1 = WoT + (long long)D * HD;             // [4096,4096]
    u16* buf2 = buf1 + (long long)BS * HD;

    dim3 blk(256);

    // 0) prep: x -> bf16, weights -> transposed bf16
    cvt_kernel<<<dim3(BS * D / 1024), blk, 0, stream>>>(x, xb);
    wtrans_kernel<<<dim3(HD / 64, D / 64), blk, 0, stream>>>(Wq, WqT, D, HD);
    wtrans_kernel<<<dim3(HD / 64, D / 64), blk, 0, stream>>>(Wk, WkT, D, HD);
    wtrans_kernel<<<dim3(HD / 64, D / 64), blk, 0, stream>>>(Wv, WvT, D, HD);
    wtrans_kernel<<<dim3(D / 64, HD / 64), blk, 0, stream>>>(Wo, WoT, HD, D);

    // 1) q = xb @ WqT^T -> buf1 ; k = xb @ WkT^T -> buf2
    {
        dim3 g(HD / BN, BS / BM, 1);
        gemm_bt<false,false><<<g, blk, 0, stream>>>(
            xb, D, 0, 0, WqT, D, 0, 0, buf1, HD, 0, 0, D, bq, 1.0f, 1);
        gemm_bt<false,false><<<g, blk, 0, stream>>>(
            xb, D, 0, 0, WkT, D, 0, 0, buf2, HD, 0, 0, D, bk, 1.0f, 1);
    }
    // 2) scores = q @ k^T / 512 per (h,b) -> fp32 attn region
    {
        dim3 g(S / BN, S / BM, H * B);
        gemm_bt<false,true><<<g, blk, 0, stream>>>(
            buf1, HD, D, (long long)S * HD,
            buf2, HD, D, (long long)S * HD,
            attn, S, (long long)B * S * S, (long long)S * S,
            D, nullptr, 1.0f / (float)D, B);
    }
    // 3) row softmax in place
    softmax_kernel<<<dim3(H * B * S), blk, 0, stream>>>(attn);
    // 4) v = xb @ WvT^T -> buf1 (q dead) ; transpose -> vT in buf2 (k dead)
    {
        dim3 g(HD / BN, BS / BM, 1);
        gemm_bt<false,false><<<g, blk, 0, stream>>>(
            xb, D, 0, 0, WvT, D, 0, 0, buf1, HD, 0, 0, D, bv, 1.0f, 1);
        vtrans_kernel<<<dim3(S / 64, D / 64, H * B), blk, 0, stream>>>(buf1, buf2);
    }
    // 5) ctx = attn @ vT^T per (h,b) -> buf1 bf16 (vb dead)
    {
        dim3 g(D / BN, S / BM, H * B);
        gemm_bt<true,false><<<g, blk, 0, stream>>>(
            attn, S, (long long)B * S * S, (long long)S * S,
            buf2, S, (long long)B * D * S, (long long)D * S,
            buf1, HD, D, (long long)S * HD,
            S, nullptr, 1.0f, B);
    }
    // 6) out = ctx @ WoT^T + bo -> fp32
    {
        dim3 g(D / BN, BS / BM, 1);
        gemm_bt<false,true><<<g, blk, 0, stream>>>(
            buf1, HD, 0, 0, WoT, HD, 0, 0, out, D, 0, 0, HD, bo, 1.0f, 1);
    }
}

// Round 3
// 581.575 us; speedup vs baseline: 2.0588x; 1.0818x over previous
//
#include <hip/hip_runtime.h>

// MultiHeadSelfAttention: B=4, S=1024, D=512(d_model = per-head dim), H=8
// out  = [B*S, D]    fp32 at d_out
// attn = [H*B, S, S] fp32 at d_out + B*S*D
//
// All GEMMs are BT (B given as [N][K] bf16, k-contiguous).
// V is computed directly transposed (vT[hb][d][s]) via a row-bias GEMM.
//
// d_ws layout (87.1 MB <= 100.7 MB proven available):
//   xb   bf16 [4096,512]    4 MB
//   WqT  bf16 [4096,512]    4 MB
//   WkT  bf16 [4096,512]    4 MB
//   WvT  bf16 [4096,512]    4 MB
//   WoT  bf16 [512,4096]    4 MB
//   buf1 bf16 [4096,4096]  33.5 MB   (q  -> vT)
//   buf2 bf16 [4096,4096]  33.5 MB   (k  -> ctx)

typedef unsigned short u16;
typedef __attribute__((ext_vector_type(8))) short short8;
typedef __attribute__((ext_vector_type(4))) float f32x4;
typedef __attribute__((ext_vector_type(2))) unsigned int u32x2;

#define BK 32

__device__ __forceinline__ u16 f2bf(float f) {
    union { float f; unsigned u; } v; v.f = f;
    unsigned u = v.u;
    u += 0x7fffu + ((u >> 16) & 1u);   // round-to-nearest-even
    return (u16)(u >> 16);
}

__device__ __forceinline__ void gl2lds16(const void* g, void* l) {
    __builtin_amdgcn_global_load_lds(
        (const __attribute__((address_space(1))) void*)g,
        (__attribute__((address_space(3))) void*)l, 16, 0, 0);
}

// C = scale * (A @ B^T) + bias.  A:[M,K] (fp32 or bf16), B:[N,K] bf16.
// Tile: BM=MF*32 x BN=NF*32, 4 waves in 2x2, BK=32, 16x16x32 bf16 MFMA.
// Batch via blockIdx.z: zh = z/nb, zb = z%nb.
template<int MF, int NF, bool AF32, bool OUTF32, bool ROWBIAS>
__global__ __launch_bounds__(256)
void gemm_bt(const void* __restrict__ Ap, int lda, long long sAh, long long sAb,
             const u16* __restrict__ Bp, int ldb, long long sBh, long long sBb,
             void* __restrict__ Cp, int ldc, long long sCh, long long sCb,
             int K, const float* __restrict__ bias, long long sbias,
             float scale, int nb)
{
    constexpr int BMt = MF * 32, BNt = NF * 32;
    __shared__ __attribute__((aligned(16))) u16 Alds[BMt][BK];   // [m][k]
    __shared__ __attribute__((aligned(16))) u16 Blds[BNt][BK];   // [n][k]

    const int z  = blockIdx.z;
    const int zh = z / nb, zb = z % nb;

    const int m0 = blockIdx.y * BMt;
    const int n0 = blockIdx.x * BNt;

    const int tid  = threadIdx.x;
    const int lane = tid & 63;
    const int wave = tid >> 6;
    const int wm = (wave >> 1) * (MF * 16);
    const int wn = (wave & 1) * (NF * 16);

    const float* Afp = (const float*)Ap + (long long)zh * sAh + (long long)zb * sAb;
    const u16*   Abf = (const u16*)Ap + (long long)zh * sAh + (long long)zb * sAb;
    const u16*   Bbf = Bp + (long long)zh * sBh + (long long)zb * sBb;

    f32x4 acc[MF][NF] = {};

    for (int kt = 0; kt < K; kt += BK) {
        __syncthreads();
        // ---- stage A tile -> Alds[m][k] ----
        if (AF32) {
            #pragma unroll
            for (int i = 0; i < BMt / 32; ++i) {
                int idx = i * 256 + tid;
                int row = idx >> 3;
                int kq  = (idx & 7) << 2;
                f32x4 v = *(const f32x4*)(Afp + (long long)(m0 + row) * lda + (kt + kq));
                u32x2 p;
                p.x = (unsigned)f2bf(v.x) | ((unsigned)f2bf(v.y) << 16);
                p.y = (unsigned)f2bf(v.z) | ((unsigned)f2bf(v.w) << 16);
                *(u32x2*)(&Alds[row][kq]) = p;
            }
        } else {
            #pragma unroll
            for (int i = 0; i < BMt / 64; ++i) {
                int idx = i * 256 + tid;
                int row = idx >> 2;
                int kq  = (idx & 3) << 3;
                gl2lds16(Abf + (long long)(m0 + row) * lda + (kt + kq), &Alds[row][kq]);
            }
        }
        // ---- stage B tile -> Blds[n][k] ----
        #pragma unroll
        for (int i = 0; i < BNt / 64; ++i) {
            int idx = i * 256 + tid;
            int row = idx >> 2;
            int kq  = (idx & 3) << 3;
            gl2lds16(Bbf + (long long)(n0 + row) * ldb + (kt + kq), &Blds[row][kq]);
        }
        __syncthreads();

        // ---- compute: MF x NF tiles of 16x16x32 MFMA ----
        const int kq = (lane >> 4) << 3;
        const int fr = lane & 15;
        short8 af[MF], bfr[NF];
        #pragma unroll
        for (int im = 0; im < MF; ++im)
            af[im] = *(const short8*)(&Alds[wm + im * 16 + fr][kq]);
        #pragma unroll
        for (int in = 0; in < NF; ++in)
            bfr[in] = *(const short8*)(&Blds[wn + in * 16 + fr][kq]);
        #pragma unroll
        for (int im = 0; im < MF; ++im)
            #pragma unroll
            for (int in = 0; in < NF; ++in)
                acc[im][in] = __builtin_amdgcn_mfma_f32_16x16x32_bf16(
                    af[im], bfr[in], acc[im][in], 0, 0, 0);
    }

    // ---- epilogue: C[row=(lane>>4)*4+r][col=lane&15] ----
    float* Cfp = (float*)Cp + (long long)zh * sCh + (long long)zb * sCb;
    u16*   Cbf = (u16*)Cp + (long long)zh * sCh + (long long)zb * sCb;
    const float* biasp = bias ? bias + (long long)zh * sbias : nullptr;
    const int rb  = (lane >> 4) << 2;
    const int col = lane & 15;
    #pragma unroll
    for (int im = 0; im < MF; ++im) {
        #pragma unroll
        for (int r = 0; r < 4; ++r) {
            int row = m0 + wm + im * 16 + rb + r;
            float rbias = (biasp && ROWBIAS) ? biasp[row] : 0.0f;
            #pragma unroll
            for (int in = 0; in < NF; ++in) {
                int cc = n0 + wn + in * 16 + col;
                float v = acc[im][in][r] * scale;
                if (biasp) v += ROWBIAS ? rbias : biasp[cc];
                if (OUTF32) Cfp[(long long)row * ldc + cc] = v;
                else        Cbf[(long long)row * ldc + cc] = f2bf(v);
            }
        }
    }
}

// In-place softmax over rows of 1024 fp32. One 256-thread block per row.
__global__ __launch_bounds__(256)
void softmax_kernel(float* __restrict__ attn)
{
    const long long row = blockIdx.x;
    float* p = attn + row * 1024;
    const int tid  = threadIdx.x;
    const int lane = tid & 63;
    const int wave = tid >> 6;
    __shared__ float red[8];

    f32x4 v = *(f32x4*)(p + tid * 4);
    float mx = fmaxf(fmaxf(v.x, v.y), fmaxf(v.z, v.w));
    #pragma unroll
    for (int off = 1; off < 64; off <<= 1)
        mx = fmaxf(mx, __shfl_xor(mx, off, 64));
    if (lane == 0) red[wave] = mx;
    __syncthreads();
    mx = fmaxf(fmaxf(red[0], red[1]), fmaxf(red[2], red[3]));

    v.x = __expf(v.x - mx);
    v.y = __expf(v.y - mx);
    v.z = __expf(v.z - mx);
    v.w = __expf(v.w - mx);
    float s = v.x + v.y + v.z + v.w;
    #pragma unroll
    for (int off = 1; off < 64; off <<= 1)
        s += __shfl_xor(s, off, 64);
    if (lane == 0) red[4 + wave] = s;
    __syncthreads();
    s = red[4] + red[5] + red[6] + red[7];
    float inv = 1.0f / s;
    v.x *= inv; v.y *= inv; v.z *= inv; v.w *= inv;
    *(f32x4*)(p + tid * 4) = v;
}

// x fp32 -> bf16 elementwise
__global__ __launch_bounds__(256)
void cvt_kernel(const float* __restrict__ in, u16* __restrict__ out)
{
    long long i = (long long)blockIdx.x * 256 + threadIdx.x;
    f32x4 v = *(const f32x4*)(in + i * 4);
    u32x2 p;
    p.x = (unsigned)f2bf(v.x) | ((unsigned)f2bf(v.y) << 16);
    p.y = (unsigned)f2bf(v.z) | ((unsigned)f2bf(v.w) << 16);
    *(u32x2*)(out + i * 4) = p;
}

// transpose fp32 [R][C] -> bf16 [C][R]; 64x64 tiles, grid (C/64, R/64)
__global__ __launch_bounds__(256)
void wtrans_kernel(const float* __restrict__ in, u16* __restrict__ out, int R, int C)
{
    __shared__ __attribute__((aligned(16))) u16 t[64][72];
    const int r0 = blockIdx.y * 64, c0 = blockIdx.x * 64;
    const int tid = threadIdx.x;
    const int lr = tid >> 4;
    const int lc = (tid & 15) << 2;
    #pragma unroll
    for (int j = 0; j < 4; ++j) {
        int rr = lr + j * 16;
        f32x4 v = *(const f32x4*)(in + (long long)(r0 + rr) * C + c0 + lc);
        u32x2 p;
        p.x = (unsigned)f2bf(v.x) | ((unsigned)f2bf(v.y) << 16);
        p.y = (unsigned)f2bf(v.z) | ((unsigned)f2bf(v.w) << 16);
        *(u32x2*)(&t[rr][lc]) = p;
    }
    __syncthreads();
    const int oc = tid >> 2;
    const int rs = (tid & 3) << 4;
    union { short8 v; u16 e[8]; } a, b;
    #pragma unroll
    for (int j = 0; j < 8; ++j) a.e[j] = t[rs + j][oc];
    #pragma unroll
    for (int j = 0; j < 8; ++j) b.e[j] = t[rs + 8 + j][oc];
    u16* o = out + (long long)(c0 + oc) * R + r0 + rs;
    *(short8*)o = a.v;
    *(short8*)(o + 8) = b.v;
}

extern "C" void kernel_launch(void* const* d_in, const int* in_sizes, int n_in,
                              void* d_out, int out_size, void* d_ws, size_t ws_size,
                              hipStream_t stream)
{
    const float* x  = (const float*)d_in[0];
    const float* Wq = (const float*)d_in[1];
    const float* bq = (const float*)d_in[2];
    const float* Wk = (const float*)d_in[3];
    const float* bk = (const float*)d_in[4];
    const float* Wv = (const float*)d_in[5];
    const float* bv = (const float*)d_in[6];
    const float* Wo = (const float*)d_in[7];
    const float* bo = (const float*)d_in[8];

    const int B = 4, S = 1024, D = 512, H = 8;
    const int HD = H * D;   // 4096
    const int BS = B * S;   // 4096

    float* out  = (float*)d_out;                     // [4096, 512]
    float* attn = out + (long long)BS * D;           // [32, 1024, 1024]

    u16* xb   = (u16*)d_ws;                          // [4096,512]
    u16* WqT  = xb  + (long long)BS * D;
    u16* WkT  = WqT + (long long)HD * D;
    u16* WvT  = WkT + (long long)HD * D;
    u16* WoT  = WvT + (long long)HD * D;             // [512,4096]
    u16* buf1 = WoT + (long long)D * HD;             // [4096,4096]
    u16* buf2 = buf1 + (long long)BS * HD;

    dim3 blk(256);

    // 0) prep: x -> bf16, weights -> transposed bf16
    cvt_kernel<<<dim3(BS * D / 1024), blk, 0, stream>>>(x, xb);
    wtrans_kernel<<<dim3(HD / 64, D / 64), blk, 0, stream>>>(Wq, WqT, D, HD);
    wtrans_kernel<<<dim3(HD / 64, D / 64), blk, 0, stream>>>(Wk, WkT, D, HD);
    wtrans_kernel<<<dim3(HD / 64, D / 64), blk, 0, stream>>>(Wv, WvT, D, HD);
    wtrans_kernel<<<dim3(D / 64, HD / 64), blk, 0, stream>>>(Wo, WoT, HD, D);

    // 1) q = xb @ WqT^T -> buf1 ; k = xb @ WkT^T -> buf2   [128x128 tiles]
    {
        dim3 g(HD / 128, BS / 128, 1);
        gemm_bt<4,4,false,false,false><<<g, blk, 0, stream>>>(
            xb, D, 0, 0, WqT, D, 0, 0, buf1, HD, 0, 0, D, bq, 0, 1.0f, 1);
        gemm_bt<4,4,false,false,false><<<g, blk, 0, stream>>>(
            xb, D, 0, 0, WkT, D, 0, 0, buf2, HD, 0, 0, D, bk, 0, 1.0f, 1);
    }
    // 2) scores = q @ k^T / 512 per (h,b) -> fp32 attn region
    {
        dim3 g(S / 128, S / 128, H * B);
        gemm_bt<4,4,false,true,false><<<g, blk, 0, stream>>>(
            buf1, HD, D, (long long)S * HD,
            buf2, HD, D, (long long)S * HD,
            attn, S, (long long)B * S * S, (long long)S * S,
            D, nullptr, 0, 1.0f / (float)D, B);
    }
    // 3) row softmax in place
    softmax_kernel<<<dim3(H * B * S), blk, 0, stream>>>(attn);
    // 4) vT[hb][d][s] = Wv^T slice @ xb^T + bv  -> buf1 (q dead); row bias
    {
        dim3 g(S / 128, D / 128, H * B);
        gemm_bt<4,4,false,false,true><<<g, blk, 0, stream>>>(
            WvT, D, (long long)D * D, 0,
            xb, D, 0, (long long)S * D,
            buf1, S, (long long)B * D * S, (long long)D * S,
            D, bv, D, 1.0f, B);
    }
    // 5) ctx = attn @ vT^T per (h,b) -> buf2 bf16 (k dead)   [128x256 tiles]
    {
        dim3 g(D / 256, S / 128, H * B);
        gemm_bt<4,8,true,false,false><<<g, blk, 0, stream>>>(
            attn, S, (long long)B * S * S, (long long)S * S,
            buf1, S, (long long)B * D * S, (long long)D * S,
            buf2, HD, D, (long long)S * HD,
            S, nullptr, 0, 1.0f, B);
    }
    // 6) out = ctx @ WoT^T + bo -> fp32   [64x128 tiles, 256 blocks]
    {
        dim3 g(D / 128, BS / 64, 1);
        gemm_bt<2,4,false,true,false><<<g, blk, 0, stream>>>(
            buf2, HD, 0, 0, WoT, HD, 0, 0, out, D, 0, 0, HD, bo, 0, 1.0f, 1);
    }
}